// Round 1
// baseline (1210.330 us; speedup 1.0000x reference)
//
#include <hip/hip_runtime.h>

#define D 128

// ---------------- CSR build ----------------

__global__ void deg_kernel(const int* __restrict__ ei, int E, int* __restrict__ deg) {
    int e = blockIdx.x * blockDim.x + threadIdx.x;
    if (e < E) atomicAdd(&deg[ei[E + e]], 1);
}

__global__ __launch_bounds__(1024) void scan_kernel(const int* __restrict__ deg, int N,
                                                    int* __restrict__ row_start) {
    __shared__ int wsum[16];
    __shared__ int carry_s;
    __shared__ int total_s;
    int tid = threadIdx.x, lane = tid & 63, wid = tid >> 6;
    if (tid == 0) carry_s = 0;
    __syncthreads();
    for (int base = 0; base < N; base += 1024) {
        int i = base + tid;
        int v = (i < N) ? deg[i] : 0;
        int x = v;
        #pragma unroll
        for (int off = 1; off < 64; off <<= 1) {
            int t = __shfl_up(x, off);
            if (lane >= off) x += t;
        }
        if (lane == 63) wsum[wid] = x;
        __syncthreads();                       // (A)
        if (tid == 0) {
            int acc = 0;
            #pragma unroll
            for (int w = 0; w < 16; ++w) { int t = wsum[w]; wsum[w] = acc; acc += t; }
            total_s = acc;
        }
        __syncthreads();                       // (B)
        int excl = carry_s + wsum[wid] + (x - v);
        if (i < N) row_start[i] = excl;
        __syncthreads();                       // (C) everyone has read carry_s
        if (tid == 0) carry_s += total_s;
        __syncthreads();
    }
    if (tid == 0) row_start[N] = carry_s;
}

__global__ void scatter_kernel(const int* __restrict__ ei, int E,
                               const int* __restrict__ row_start,
                               int* __restrict__ cursor, int* __restrict__ col) {
    int e = blockIdx.x * blockDim.x + threadIdx.x;
    if (e < E) {
        int d = ei[E + e];
        int p = atomicAdd(&cursor[d], 1);
        col[row_start[d] + p] = ei[e];
    }
}

// ---------------- weight transpose (W[j][k] -> WT[k][j]) ----------------

__global__ void transpose128_kernel(const float* __restrict__ W, float* __restrict__ WT) {
    int idx = blockIdx.x * 256 + threadIdx.x;   // 64 blocks x 256 = 16384
    int j = idx >> 7, k = idx & 127;
    WT[k * D + j] = W[idx];
}

// ---------------- mean aggregation over CSR ----------------
// one wave (64 lanes) per node, float2 per lane = 128 floats

__global__ __launch_bounds__(256) void agg_kernel(const float* __restrict__ h,
                                                  const int* __restrict__ row_start,
                                                  const int* __restrict__ col,
                                                  float* __restrict__ agg, int N) {
    int node = blockIdx.x * 4 + (threadIdx.x >> 6);
    if (node >= N) return;
    int lane = threadIdx.x & 63;
    int s0 = row_start[node], s1 = row_start[node + 1];
    const float2* h2 = (const float2*)h;
    float ax = 0.f, ay = 0.f;
    for (int p = s0; p < s1; ++p) {
        int src = col[p];
        float2 v = h2[(size_t)src * 64 + lane];
        ax += v.x; ay += v.y;
    }
    float inv = 1.0f / fmaxf((float)(s1 - s0), 1.0f);
    float2 o; o.x = ax * inv; o.y = ay * inv;
    ((float2*)agg)[(size_t)node * 64 + lane] = o;
}

// ---------------- fused dual GEMM: out = [relu](agg@WlT + bl + h@WrT) ----------------
// block: 256 threads, 16 nodes; thread = (half, j); 8 node-accumulators each.

template <bool RELU>
__global__ __launch_bounds__(256) void gemm_fused(const float* __restrict__ agg,
                                                  const float* __restrict__ h,
                                                  const float* __restrict__ WlT,
                                                  const float* __restrict__ WrT,
                                                  const float* __restrict__ bias,
                                                  float* __restrict__ out, int N) {
    __shared__ float s_agg[16 * D];
    __shared__ float s_h[16 * D];
    int base = blockIdx.x * 16;
    int tid = threadIdx.x;
    int nrows = N - base; if (nrows > 16) nrows = 16;

    float4* sa4 = (float4*)s_agg;
    float4* sh4 = (float4*)s_h;
    #pragma unroll
    for (int t = 0; t < 2; ++t) {
        int e = tid + t * 256;          // float4 index in [0,512)
        int row = e >> 5;               // 32 float4 per row
        int c4 = e & 31;
        if (row < nrows) {
            sa4[e] = *(const float4*)(agg + (size_t)(base + row) * D + c4 * 4);
            sh4[e] = *(const float4*)(h   + (size_t)(base + row) * D + c4 * 4);
        } else {
            float4 z; z.x = z.y = z.z = z.w = 0.f;
            sa4[e] = z; sh4[e] = z;
        }
    }
    __syncthreads();

    int j = tid & 127;
    int half = tid >> 7;
    const float* sa = s_agg + half * 8 * D;
    const float* sh = s_h + half * 8 * D;

    float acc[8];
    #pragma unroll
    for (int n = 0; n < 8; ++n) acc[n] = 0.f;

    for (int k = 0; k < D; k += 4) {
        float wl0 = WlT[(k + 0) * D + j];
        float wl1 = WlT[(k + 1) * D + j];
        float wl2 = WlT[(k + 2) * D + j];
        float wl3 = WlT[(k + 3) * D + j];
        float wr0 = WrT[(k + 0) * D + j];
        float wr1 = WrT[(k + 1) * D + j];
        float wr2 = WrT[(k + 2) * D + j];
        float wr3 = WrT[(k + 3) * D + j];
        #pragma unroll
        for (int n = 0; n < 8; ++n) {
            float4 a = *(const float4*)(sa + n * D + k);
            float4 hh = *(const float4*)(sh + n * D + k);
            acc[n] += a.x * wl0 + a.y * wl1 + a.z * wl2 + a.w * wl3
                    + hh.x * wr0 + hh.y * wr1 + hh.z * wr2 + hh.w * wr3;
        }
    }

    float b = bias[j];
    #pragma unroll
    for (int n = 0; n < 8; ++n) {
        int node = base + half * 8 + n;
        if (node < N) {
            float v = acc[n] + b;
            if (RELU) v = fmaxf(v, 0.f);
            out[(size_t)node * D + j] = v;
        }
    }
}

// ---------------- launch ----------------

extern "C" void kernel_launch(void* const* d_in, const int* in_sizes, int n_in,
                              void* d_out, int out_size, void* d_ws, size_t ws_size,
                              hipStream_t stream) {
    const float* x   = (const float*)d_in[0];
    const int*   ei  = (const int*)d_in[1];
    const float* Wl0 = (const float*)d_in[2];
    const float* bl0 = (const float*)d_in[3];
    const float* Wr0 = (const float*)d_in[4];
    const float* Wl1 = (const float*)d_in[5];
    const float* bl1 = (const float*)d_in[6];
    const float* Wr1 = (const float*)d_in[7];
    const float* Wl2 = (const float*)d_in[8];
    const float* bl2 = (const float*)d_in[9];
    const float* Wr2 = (const float*)d_in[10];

    const int N = in_sizes[0] / D;
    const int E = in_sizes[1] / 2;

    char* ws = (char*)d_ws;
    size_t off = 0;
    auto alloc = [&](size_t bytes) {
        void* p = ws + off;
        off = (off + bytes + 255) & ~(size_t)255;
        return p;
    };
    float* bufA      = (float*)alloc((size_t)N * D * 4);
    float* aggb      = (float*)alloc((size_t)N * D * 4);
    float* WT        = (float*)alloc(6 * (size_t)D * D * 4);
    int*   deg       = (int*)alloc((size_t)N * 4);
    int*   row_start = (int*)alloc((size_t)(N + 1) * 4);
    int*   cursor    = (int*)alloc((size_t)N * 4);
    int*   col       = (int*)alloc((size_t)E * 4);
    (void)ws_size; (void)n_in; (void)out_size;

    hipMemsetAsync(deg, 0, (size_t)N * 4, stream);
    hipMemsetAsync(cursor, 0, (size_t)N * 4, stream);

    const float* Ws[6] = {Wl0, Wr0, Wl1, Wr1, Wl2, Wr2};
    for (int m = 0; m < 6; ++m)
        transpose128_kernel<<<64, 256, 0, stream>>>(Ws[m], WT + (size_t)m * D * D);

    int eb = (E + 255) / 256;
    deg_kernel<<<eb, 256, 0, stream>>>(ei, E, deg);
    scan_kernel<<<1, 1024, 0, stream>>>(deg, N, row_start);
    scatter_kernel<<<eb, 256, 0, stream>>>(ei, E, row_start, cursor, col);

    float* out = (float*)d_out;
    int agrid = (N + 3) / 4;
    int ggrid = (N + 15) / 16;

    // layer 0: x -> bufA (relu)
    agg_kernel<<<agrid, 256, 0, stream>>>(x, row_start, col, aggb, N);
    gemm_fused<true><<<ggrid, 256, 0, stream>>>(aggb, x, WT + 0 * D * D, WT + 1 * D * D, bl0, bufA, N);

    // layer 1: bufA -> out (relu)
    agg_kernel<<<agrid, 256, 0, stream>>>(bufA, row_start, col, aggb, N);
    gemm_fused<true><<<ggrid, 256, 0, stream>>>(aggb, bufA, WT + 2 * D * D, WT + 3 * D * D, bl1, out, N);

    // layer 2: out -> out (no relu), in-place safe (rows staged in LDS first)
    agg_kernel<<<agrid, 256, 0, stream>>>(out, row_start, col, aggb, N);
    gemm_fused<false><<<ggrid, 256, 0, stream>>>(aggb, out, WT + 4 * D * D, WT + 5 * D * D, bl2, out, N);
}

// Round 2
// 529.488 us; speedup vs baseline: 2.2858x; 2.2858x over previous
//
#include <hip/hip_runtime.h>

#define D 128

typedef unsigned int u32;
typedef unsigned short u16;
typedef __attribute__((ext_vector_type(8))) short bf16x8;
typedef __attribute__((ext_vector_type(4))) float f32x4;

static __device__ __forceinline__ u16 f2bf(float x) {
    u32 u = __float_as_uint(x);
    u32 r = (u + 0x7fffu + ((u >> 16) & 1u)) >> 16;   // RNE
    return (u16)r;
}
static __device__ __forceinline__ float bf_lo(u32 u) { return __uint_as_float(u << 16); }
static __device__ __forceinline__ float bf_hi(u32 u) { return __uint_as_float(u & 0xffff0000u); }
static __device__ __forceinline__ u32 pack_bf(float lo, float hi) {
    return (u32)f2bf(lo) | ((u32)f2bf(hi) << 16);
}

// ---------------- CSR build ----------------

__global__ void deg_kernel(const int* __restrict__ ei, int E, int* __restrict__ deg) {
    int e = blockIdx.x * blockDim.x + threadIdx.x;
    if (e < E) atomicAdd(&deg[ei[E + e]], 1);
}

__global__ __launch_bounds__(1024) void scan_kernel(const int* __restrict__ deg, int N,
                                                    int* __restrict__ row_start) {
    __shared__ int wsum[16];
    __shared__ int carry_s;
    __shared__ int total_s;
    int tid = threadIdx.x, lane = tid & 63, wid = tid >> 6;
    if (tid == 0) carry_s = 0;
    __syncthreads();
    for (int base = 0; base < N; base += 1024) {
        int i = base + tid;
        int v = (i < N) ? deg[i] : 0;
        int x = v;
        #pragma unroll
        for (int off = 1; off < 64; off <<= 1) {
            int t = __shfl_up(x, off);
            if (lane >= off) x += t;
        }
        if (lane == 63) wsum[wid] = x;
        __syncthreads();
        if (tid == 0) {
            int acc = 0;
            #pragma unroll
            for (int w = 0; w < 16; ++w) { int t = wsum[w]; wsum[w] = acc; acc += t; }
            total_s = acc;
        }
        __syncthreads();
        int excl = carry_s + wsum[wid] + (x - v);
        if (i < N) row_start[i] = excl;
        __syncthreads();
        if (tid == 0) carry_s += total_s;
        __syncthreads();
    }
    if (tid == 0) row_start[N] = carry_s;
}

__global__ void scatter_kernel(const int* __restrict__ ei, int E,
                               const int* __restrict__ row_start,
                               int* __restrict__ cursor, int* __restrict__ col) {
    int e = blockIdx.x * blockDim.x + threadIdx.x;
    if (e < E) {
        int d = ei[E + e];
        int p = atomicAdd(&cursor[d], 1);
        col[row_start[d] + p] = ei[e];
    }
}

// ---------------- conversions ----------------

// 8 floats -> 8 bf16 per thread
__global__ void to_bf16_kernel(const float* __restrict__ in, u32* __restrict__ out, int n8) {
    int i = blockIdx.x * 256 + threadIdx.x;
    if (i >= n8) return;
    const float4* p = (const float4*)in + (size_t)i * 2;
    float4 a = p[0], b = p[1];
    uint4 o;
    o.x = pack_bf(a.x, a.y);
    o.y = pack_bf(a.z, a.w);
    o.z = pack_bf(b.x, b.y);
    o.w = pack_bf(b.z, b.w);
    ((uint4*)out)[i] = o;
}

// Wcat[j][k] (k in [0,256)): Wl[j][k] for k<128 else Wr[j][k-128]; bf16 row-major [128][256]
__global__ void build_wcat(const float* __restrict__ Wl, const float* __restrict__ Wr,
                           u16* __restrict__ Wcat) {
    int idx = blockIdx.x * 256 + threadIdx.x;   // 32768 total
    int j = idx >> 8, k = idx & 255;
    float v = (k < 128) ? Wl[j * 128 + k] : Wr[j * 128 + (k - 128)];
    Wcat[idx] = f2bf(v);
}

// ---------------- mean aggregation (bf16 in, bf16 out) ----------------
// one wave per node; lane handles 2 channels (one u32)

__global__ __launch_bounds__(256) void agg_bf16(const u32* __restrict__ h32, // [N][64]
                                                const int* __restrict__ row_start,
                                                const int* __restrict__ col,
                                                u32* __restrict__ agg32, int N) {
    int node = blockIdx.x * 4 + (threadIdx.x >> 6);
    node = __builtin_amdgcn_readfirstlane(node);
    if (node >= N) return;
    int lane = threadIdx.x & 63;
    int s0 = row_start[node], s1 = row_start[node + 1];
    float ax = 0.f, ay = 0.f;
    int p = s0;
    for (; p + 4 <= s1; p += 4) {
        int c0 = col[p], c1 = col[p + 1], c2 = col[p + 2], c3 = col[p + 3];
        u32 u0 = h32[(size_t)c0 * 64 + lane];
        u32 u1 = h32[(size_t)c1 * 64 + lane];
        u32 u2 = h32[(size_t)c2 * 64 + lane];
        u32 u3 = h32[(size_t)c3 * 64 + lane];
        ax += bf_lo(u0) + bf_lo(u1) + bf_lo(u2) + bf_lo(u3);
        ay += bf_hi(u0) + bf_hi(u1) + bf_hi(u2) + bf_hi(u3);
    }
    for (; p < s1; ++p) {
        u32 u = h32[(size_t)col[p] * 64 + lane];
        ax += bf_lo(u);
        ay += bf_hi(u);
    }
    float inv = 1.0f / fmaxf((float)(s1 - s0), 1.0f);
    agg32[(size_t)node * 64 + lane] = pack_bf(ax * inv, ay * inv);
}

// ---------------- fused dual GEMM via MFMA ----------------
// out[n,j] = [relu]( sum_k A[n,k]*Wcat[j,k] + bias[j] ),  A = [agg | h], K=256
// block: 256 thr = 4 waves; tile 64 rows x 128 cols; wave w: cols [w*32, w*32+32)

template <bool RELU, bool OUT_F32>
__global__ __launch_bounds__(256) void gemm_mfma(const u16* __restrict__ aggb,  // [N][128]
                                                 const u16* __restrict__ hb,    // [N][128]
                                                 const u16* __restrict__ Wcat,  // [128][256]
                                                 const float* __restrict__ bias,
                                                 u16* __restrict__ out_bf,
                                                 float* __restrict__ out_f32, int N) {
    __shared__ u16 s_a[64 * 256];   // 32 KB, XOR-swizzled rows
    int tid = threadIdx.x;
    int base = blockIdx.x * 64;
    int nrows = N - base; if (nrows > 64) nrows = 64;

    // stage A: 64 rows x 512 B = 2048 x 16B chunks, 8 per thread
    #pragma unroll
    for (int i = 0; i < 8; ++i) {
        int c = tid + i * 256;
        int row = c >> 5;          // 32 chunks per row
        int c16 = c & 31;
        int kbyte = (c16 * 16) ^ ((row & 7) << 4);
        uint4 v = make_uint4(0u, 0u, 0u, 0u);
        if (row < nrows) {
            const u16* src = (c16 < 16) ? (aggb + (size_t)(base + row) * 128 + c16 * 8)
                                        : (hb + (size_t)(base + row) * 128 + (c16 - 16) * 8);
            v = *(const uint4*)src;
        }
        *(uint4*)((char*)s_a + row * 512 + kbyte) = v;
    }
    __syncthreads();

    int lane = tid & 63;
    int wid = tid >> 6;
    int colbase = wid * 32;
    int jb = lane & 15;
    int kq = (lane >> 4) * 8;       // k sub-offset within 32

    // B fragments: Wcat rows are [j][k], exactly the B^T layout MFMA wants
    bf16x8 bfr[8][2];
    #pragma unroll
    for (int ks = 0; ks < 8; ++ks)
        #pragma unroll
        for (int n = 0; n < 2; ++n) {
            int j = colbase + n * 16 + jb;
            bfr[ks][n] = *(const bf16x8*)(Wcat + (size_t)j * 256 + ks * 32 + kq);
        }

    f32x4 acc[4][2];
    #pragma unroll
    for (int m = 0; m < 4; ++m)
        #pragma unroll
        for (int n = 0; n < 2; ++n)
            acc[m][n] = (f32x4){0.f, 0.f, 0.f, 0.f};

    #pragma unroll
    for (int ks = 0; ks < 8; ++ks) {
        bf16x8 afr[4];
        #pragma unroll
        for (int m = 0; m < 4; ++m) {
            int row = m * 16 + jb;
            int kbyte = (ks * 64 + kq * 2) ^ ((row & 7) << 4);
            afr[m] = *(const bf16x8*)((const char*)s_a + row * 512 + kbyte);
        }
        #pragma unroll
        for (int m = 0; m < 4; ++m)
            #pragma unroll
            for (int n = 0; n < 2; ++n)
                acc[m][n] = __builtin_amdgcn_mfma_f32_16x16x32_bf16(afr[m], bfr[ks][n],
                                                                    acc[m][n], 0, 0, 0);
    }

    float bv[2];
    #pragma unroll
    for (int n = 0; n < 2; ++n) bv[n] = bias[colbase + n * 16 + jb];

    #pragma unroll
    for (int m = 0; m < 4; ++m)
        #pragma unroll
        for (int n = 0; n < 2; ++n) {
            int colj = colbase + n * 16 + jb;
            #pragma unroll
            for (int r = 0; r < 4; ++r) {
                int row = m * 16 + (lane >> 4) * 4 + r;
                if (row < nrows) {
                    float v = acc[m][n][r] + bv[n];
                    if (RELU) v = fmaxf(v, 0.f);
                    size_t o = (size_t)(base + row) * 128 + colj;
                    if (OUT_F32) out_f32[o] = v;
                    else out_bf[o] = f2bf(v);
                }
            }
        }
}

// ---------------- launch ----------------

extern "C" void kernel_launch(void* const* d_in, const int* in_sizes, int n_in,
                              void* d_out, int out_size, void* d_ws, size_t ws_size,
                              hipStream_t stream) {
    const float* x   = (const float*)d_in[0];
    const int*   ei  = (const int*)d_in[1];
    const float* Wl0 = (const float*)d_in[2];
    const float* bl0 = (const float*)d_in[3];
    const float* Wr0 = (const float*)d_in[4];
    const float* Wl1 = (const float*)d_in[5];
    const float* bl1 = (const float*)d_in[6];
    const float* Wr1 = (const float*)d_in[7];
    const float* Wl2 = (const float*)d_in[8];
    const float* bl2 = (const float*)d_in[9];
    const float* Wr2 = (const float*)d_in[10];

    const int N = in_sizes[0] / D;
    const int E = in_sizes[1] / 2;

    char* ws = (char*)d_ws;
    size_t off = 0;
    auto alloc = [&](size_t bytes) {
        void* p = ws + off;
        off = (off + bytes + 255) & ~(size_t)255;
        return p;
    };
    u16* xb        = (u16*)alloc((size_t)N * D * 2);   // layer-0 input; reused as h2b
    u16* h1b       = (u16*)alloc((size_t)N * D * 2);
    u16* aggb      = (u16*)alloc((size_t)N * D * 2);
    u16* Wcat      = (u16*)alloc(3 * (size_t)D * 256 * 2);
    int* deg       = (int*)alloc((size_t)N * 4);
    int* row_start = (int*)alloc((size_t)(N + 1) * 4);
    int* cursor    = (int*)alloc((size_t)N * 4);
    int* colv      = (int*)alloc((size_t)E * 4);
    (void)ws_size; (void)n_in; (void)out_size;
    u16* h2b = xb;   // alias: xb dead after layer-1 GEMM

    hipMemsetAsync(deg, 0, (size_t)N * 4, stream);
    hipMemsetAsync(cursor, 0, (size_t)N * 4, stream);

    // weights -> bf16 concat [Wl | Wr] per layer
    build_wcat<<<128, 256, 0, stream>>>(Wl0, Wr0, Wcat + 0 * D * 256);
    build_wcat<<<128, 256, 0, stream>>>(Wl1, Wr1, Wcat + 1 * D * 256);
    build_wcat<<<128, 256, 0, stream>>>(Wl2, Wr2, Wcat + 2 * D * 256);

    // x -> bf16
    int n8 = N * D / 8;
    to_bf16_kernel<<<(n8 + 255) / 256, 256, 0, stream>>>(x, (u32*)xb, n8);

    // CSR
    int eb = (E + 255) / 256;
    deg_kernel<<<eb, 256, 0, stream>>>(ei, E, deg);
    scan_kernel<<<1, 1024, 0, stream>>>(deg, N, row_start);
    scatter_kernel<<<eb, 256, 0, stream>>>(ei, E, row_start, cursor, colv);

    float* out = (float*)d_out;
    int agrid = (N + 3) / 4;
    int ggrid = (N + 63) / 64;

    // layer 0: xb -> h1b (relu)
    agg_bf16<<<agrid, 256, 0, stream>>>((const u32*)xb, row_start, colv, (u32*)aggb, N);
    gemm_mfma<true, false><<<ggrid, 256, 0, stream>>>(aggb, xb, Wcat + 0 * D * 256, bl0,
                                                      h1b, nullptr, N);
    // layer 1: h1b -> h2b (relu)
    agg_bf16<<<agrid, 256, 0, stream>>>((const u32*)h1b, row_start, colv, (u32*)aggb, N);
    gemm_mfma<true, false><<<ggrid, 256, 0, stream>>>(aggb, h1b, Wcat + 1 * D * 256, bl1,
                                                      h2b, nullptr, N);
    // layer 2: h2b -> d_out (f32, no relu)
    agg_bf16<<<agrid, 256, 0, stream>>>((const u32*)h2b, row_start, colv, (u32*)aggb, N);
    gemm_mfma<false, true><<<ggrid, 256, 0, stream>>>(aggb, h2b, Wcat + 2 * D * 256, bl2,
                                                      nullptr, out, N);
}

// Round 3
// 525.942 us; speedup vs baseline: 2.3013x; 1.0067x over previous
//
#include <hip/hip_runtime.h>

#define D 128

typedef unsigned int u32;
typedef unsigned short u16;
typedef __attribute__((ext_vector_type(8))) short bf16x8;
typedef __attribute__((ext_vector_type(4))) float f32x4;

static __device__ __forceinline__ u16 f2bf(float x) {
    u32 u = __float_as_uint(x);
    u32 r = (u + 0x7fffu + ((u >> 16) & 1u)) >> 16;   // RNE
    return (u16)r;
}
static __device__ __forceinline__ float bf_lo(u32 u) { return __uint_as_float(u << 16); }
static __device__ __forceinline__ float bf_hi(u32 u) { return __uint_as_float(u & 0xffff0000u); }
static __device__ __forceinline__ u32 pack_bf(float lo, float hi) {
    return (u32)f2bf(lo) | ((u32)f2bf(hi) << 16);
}

// ---------------- CSR build: rank + scan + place ----------------

// pass 1: per-edge rank within its dst; cursor ends up = deg
__global__ void rank_count_kernel(const int* __restrict__ ei, int E,
                                  int* __restrict__ cursor, int* __restrict__ rank) {
    int e = blockIdx.x * blockDim.x + threadIdx.x;
    if (e < E) rank[e] = atomicAdd(&cursor[ei[E + e]], 1);
}

// hierarchical exclusive scan of deg -> row_start
__global__ __launch_bounds__(1024) void scan_stage1(const int* __restrict__ deg, int N,
                                                    int* __restrict__ row_start,
                                                    int* __restrict__ partials) {
    __shared__ int wsum[16];
    int tid = threadIdx.x, lane = tid & 63, wid = tid >> 6;
    int i = blockIdx.x * 1024 + tid;
    int v = (i < N) ? deg[i] : 0;
    int x = v;
    #pragma unroll
    for (int off = 1; off < 64; off <<= 1) {
        int t = __shfl_up(x, off);
        if (lane >= off) x += t;
    }
    if (lane == 63) wsum[wid] = x;
    __syncthreads();
    if (tid == 0) {
        int acc = 0;
        #pragma unroll
        for (int w = 0; w < 16; ++w) { int t = wsum[w]; wsum[w] = acc; acc += t; }
        partials[blockIdx.x] = acc;
    }
    __syncthreads();
    if (i < N) row_start[i] = wsum[wid] + (x - v);
}

__global__ __launch_bounds__(1024) void scan_stage2(int* __restrict__ partials, int NB) {
    __shared__ int wsum[16];
    int tid = threadIdx.x, lane = tid & 63, wid = tid >> 6;
    int v = (tid < NB) ? partials[tid] : 0;
    int x = v;
    #pragma unroll
    for (int off = 1; off < 64; off <<= 1) {
        int t = __shfl_up(x, off);
        if (lane >= off) x += t;
    }
    if (lane == 63) wsum[wid] = x;
    __syncthreads();
    if (tid == 0) {
        int acc = 0;
        #pragma unroll
        for (int w = 0; w < 16; ++w) { int t = wsum[w]; wsum[w] = acc; acc += t; }
        partials[NB] = acc;            // grand total
    }
    __syncthreads();
    if (tid < NB) partials[tid] = wsum[wid] + (x - v);
}

__global__ __launch_bounds__(1024) void scan_stage3(int* __restrict__ row_start,
                                                    const int* __restrict__ partials,
                                                    int N, int NB) {
    int i = blockIdx.x * 1024 + threadIdx.x;
    if (i < N) row_start[i] += partials[blockIdx.x];
    if (i == 0) row_start[N] = partials[NB];
}

// pass 2: place src into col (random 4B store -> non-temporal)
__global__ void place_kernel(const int* __restrict__ ei, int E,
                             const int* __restrict__ row_start,
                             const int* __restrict__ rank, int* __restrict__ col) {
    int e = blockIdx.x * blockDim.x + threadIdx.x;
    if (e < E) {
        int d = ei[E + e];
        __builtin_nontemporal_store(ei[e], &col[row_start[d] + rank[e]]);
    }
}

// ---------------- conversions ----------------

__global__ void to_bf16_kernel(const float* __restrict__ in, u32* __restrict__ out, int n8) {
    int i = blockIdx.x * 256 + threadIdx.x;
    if (i >= n8) return;
    const float4* p = (const float4*)in + (size_t)i * 2;
    float4 a = p[0], b = p[1];
    uint4 o;
    o.x = pack_bf(a.x, a.y);
    o.y = pack_bf(a.z, a.w);
    o.z = pack_bf(b.x, b.y);
    o.w = pack_bf(b.z, b.w);
    ((uint4*)out)[i] = o;
}

// Wcat[j][k] (k in [0,256)): Wl[j][k] for k<128 else Wr[j][k-128]
__global__ void build_wcat(const float* __restrict__ Wl, const float* __restrict__ Wr,
                           u16* __restrict__ Wcat) {
    int idx = blockIdx.x * 256 + threadIdx.x;   // 32768 total
    int j = idx >> 8, k = idx & 255;
    float v = (k < 128) ? Wl[j * 128 + k] : Wr[j * 128 + (k - 128)];
    Wcat[idx] = f2bf(v);
}

// ---------------- fused layer: mean-agg -> LDS -> dual-GEMM (MFMA) ----------------
// block = 4 waves, 64 nodes. Phase 1: wave w aggregates rows [w*16, w*16+16) into the
// swizzled LDS A-tile (agg at k<128, h at k>=128). Phase 2: 64x128 MFMA GEMM vs
// Wcat[128][256] (B^T layout), bias + optional relu epilogue.

template <bool RELU, bool OUT_F32>
__global__ __launch_bounds__(256) void fused_layer(const u32* __restrict__ h32,   // [N][64]
                                                   const int* __restrict__ row_start,
                                                   const int* __restrict__ col,
                                                   const u16* __restrict__ Wcat,  // [128][256]
                                                   const float* __restrict__ bias,
                                                   u16* __restrict__ out_bf,
                                                   float* __restrict__ out_f32, int N) {
    __shared__ u16 s_a[64 * 256];   // 32 KB, XOR-swizzled within each 256B half-row
    int tid = threadIdx.x;
    int lane = tid & 63;
    int wid = tid >> 6;
    int base = blockIdx.x * 64;
    int nrows = N - base; if (nrows > 64) nrows = 64;

    // ---- phase 1: aggregation + h staging ----
    for (int rr = 0; rr < 16; ++rr) {
        int row = wid * 16 + rr;
        int node = base + row;
        if (node < N) {
            int s0 = row_start[node], s1 = row_start[node + 1];
            float ax = 0.f, ay = 0.f;
            int p = s0;
            for (; p + 8 <= s1; p += 8) {
                int c[8];
                #pragma unroll
                for (int q = 0; q < 8; ++q) c[q] = col[p + q];
                u32 u[8];
                #pragma unroll
                for (int q = 0; q < 8; ++q) u[q] = h32[(size_t)c[q] * 64 + lane];
                #pragma unroll
                for (int q = 0; q < 8; ++q) { ax += bf_lo(u[q]); ay += bf_hi(u[q]); }
            }
            for (; p + 4 <= s1; p += 4) {
                int c[4];
                #pragma unroll
                for (int q = 0; q < 4; ++q) c[q] = col[p + q];
                u32 u[4];
                #pragma unroll
                for (int q = 0; q < 4; ++q) u[q] = h32[(size_t)c[q] * 64 + lane];
                #pragma unroll
                for (int q = 0; q < 4; ++q) { ax += bf_lo(u[q]); ay += bf_hi(u[q]); }
            }
            for (; p < s1; ++p) {
                u32 u = h32[(size_t)col[p] * 64 + lane];
                ax += bf_lo(u); ay += bf_hi(u);
            }
            float inv = 1.0f / fmaxf((float)(s1 - s0), 1.0f);
            int swz = (lane * 4) ^ ((row & 7) << 4);
            *(u32*)((char*)s_a + row * 512 + swz) = pack_bf(ax * inv, ay * inv);
            *(u32*)((char*)s_a + row * 512 + 256 + swz) = h32[(size_t)node * 64 + lane];
        }
    }
    __syncthreads();

    // ---- phase 2: MFMA GEMM ----
    int colbase = wid * 32;
    int jb = lane & 15;
    int kq = (lane >> 4) * 8;

    bf16x8 bfr[8][2];
    #pragma unroll
    for (int ks = 0; ks < 8; ++ks)
        #pragma unroll
        for (int n = 0; n < 2; ++n) {
            int j = colbase + n * 16 + jb;
            bfr[ks][n] = *(const bf16x8*)(Wcat + (size_t)j * 256 + ks * 32 + kq);
        }

    f32x4 acc[4][2];
    #pragma unroll
    for (int m = 0; m < 4; ++m)
        #pragma unroll
        for (int n = 0; n < 2; ++n)
            acc[m][n] = (f32x4){0.f, 0.f, 0.f, 0.f};

    #pragma unroll
    for (int ks = 0; ks < 8; ++ks) {
        bf16x8 afr[4];
        #pragma unroll
        for (int m = 0; m < 4; ++m) {
            int row = m * 16 + jb;
            int kbyte = (ks * 64 + kq * 2) ^ ((row & 7) << 4);
            afr[m] = *(const bf16x8*)((const char*)s_a + row * 512 + kbyte);
        }
        #pragma unroll
        for (int m = 0; m < 4; ++m)
            #pragma unroll
            for (int n = 0; n < 2; ++n)
                acc[m][n] = __builtin_amdgcn_mfma_f32_16x16x32_bf16(afr[m], bfr[ks][n],
                                                                    acc[m][n], 0, 0, 0);
    }

    float bv[2];
    #pragma unroll
    for (int n = 0; n < 2; ++n) bv[n] = bias[colbase + n * 16 + jb];

    #pragma unroll
    for (int m = 0; m < 4; ++m)
        #pragma unroll
        for (int n = 0; n < 2; ++n) {
            int colj = colbase + n * 16 + jb;
            #pragma unroll
            for (int r = 0; r < 4; ++r) {
                int row = m * 16 + (lane >> 4) * 4 + r;
                if (row < nrows) {
                    float v = acc[m][n][r] + bv[n];
                    if (RELU) v = fmaxf(v, 0.f);
                    size_t o = (size_t)(base + row) * 128 + colj;
                    if (OUT_F32) out_f32[o] = v;
                    else out_bf[o] = f2bf(v);
                }
            }
        }
}

// ---------------- launch ----------------

extern "C" void kernel_launch(void* const* d_in, const int* in_sizes, int n_in,
                              void* d_out, int out_size, void* d_ws, size_t ws_size,
                              hipStream_t stream) {
    const float* x   = (const float*)d_in[0];
    const int*   ei  = (const int*)d_in[1];
    const float* Wl0 = (const float*)d_in[2];
    const float* bl0 = (const float*)d_in[3];
    const float* Wr0 = (const float*)d_in[4];
    const float* Wl1 = (const float*)d_in[5];
    const float* bl1 = (const float*)d_in[6];
    const float* Wr1 = (const float*)d_in[7];
    const float* Wl2 = (const float*)d_in[8];
    const float* bl2 = (const float*)d_in[9];
    const float* Wr2 = (const float*)d_in[10];

    const int N = in_sizes[0] / D;
    const int E = in_sizes[1] / 2;
    const int NB = (N + 1023) / 1024;

    char* ws = (char*)d_ws;
    size_t off = 0;
    auto alloc = [&](size_t bytes) {
        void* p = ws + off;
        off = (off + bytes + 255) & ~(size_t)255;
        return p;
    };
    u16* xb        = (u16*)alloc((size_t)N * D * 2);   // layer-0 input; reused as h2b
    u16* h1b       = (u16*)alloc((size_t)N * D * 2);
    u16* Wcat      = (u16*)alloc(3 * (size_t)D * 256 * 2);
    int* cursor    = (int*)alloc((size_t)N * 4);       // becomes deg
    int* row_start = (int*)alloc((size_t)(N + 1) * 4);
    int* partials  = (int*)alloc((size_t)(NB + 1) * 4);
    int* rank      = (int*)alloc((size_t)E * 4);
    int* colv      = (int*)alloc((size_t)E * 4);
    (void)ws_size; (void)n_in; (void)out_size;
    u16* h2b = xb;   // alias: xb dead after layer-1 GEMM

    hipMemsetAsync(cursor, 0, (size_t)N * 4, stream);

    // weights -> bf16 concat [Wl | Wr] per layer
    build_wcat<<<128, 256, 0, stream>>>(Wl0, Wr0, Wcat + 0 * D * 256);
    build_wcat<<<128, 256, 0, stream>>>(Wl1, Wr1, Wcat + 1 * D * 256);
    build_wcat<<<128, 256, 0, stream>>>(Wl2, Wr2, Wcat + 2 * D * 256);

    // x -> bf16
    int n8 = N * D / 8;
    to_bf16_kernel<<<(n8 + 255) / 256, 256, 0, stream>>>(x, (u32*)xb, n8);

    // CSR
    int eb = (E + 255) / 256;
    rank_count_kernel<<<eb, 256, 0, stream>>>(ei, E, cursor, rank);
    scan_stage1<<<NB, 1024, 0, stream>>>(cursor, N, row_start, partials);
    scan_stage2<<<1, 1024, 0, stream>>>(partials, NB);
    scan_stage3<<<NB, 1024, 0, stream>>>(row_start, partials, N, NB);
    place_kernel<<<eb, 256, 0, stream>>>(ei, E, row_start, rank, colv);

    float* out = (float*)d_out;
    int ggrid = (N + 63) / 64;

    // layer 0: xb -> h1b (relu)
    fused_layer<true, false><<<ggrid, 256, 0, stream>>>((const u32*)xb, row_start, colv,
                                                        Wcat + 0 * D * 256, bl0, h1b, nullptr, N);
    // layer 1: h1b -> h2b (relu)
    fused_layer<true, false><<<ggrid, 256, 0, stream>>>((const u32*)h1b, row_start, colv,
                                                        Wcat + 1 * D * 256, bl1, h2b, nullptr, N);
    // layer 2: h2b -> d_out (f32, no relu)
    fused_layer<false, true><<<ggrid, 256, 0, stream>>>((const u32*)h2b, row_start, colv,
                                                        Wcat + 2 * D * 256, bl2, nullptr, out, N);
}

// Round 4
// 399.852 us; speedup vs baseline: 3.0269x; 1.3153x over previous
//
#include <hip/hip_runtime.h>

#define D 128

typedef unsigned int u32;
typedef unsigned short u16;
typedef __attribute__((ext_vector_type(8))) short bf16x8;
typedef __attribute__((ext_vector_type(4))) float f32x4;

static __device__ __forceinline__ u16 f2bf(float x) {
    u32 u = __float_as_uint(x);
    u32 r = (u + 0x7fffu + ((u >> 16) & 1u)) >> 16;   // RNE
    return (u16)r;
}
static __device__ __forceinline__ float bf_lo(u32 u) { return __uint_as_float(u << 16); }
static __device__ __forceinline__ float bf_hi(u32 u) { return __uint_as_float(u & 0xffff0000u); }
static __device__ __forceinline__ u32 pack_bf(float lo, float hi) {
    return (u32)f2bf(lo) | ((u32)f2bf(hi) << 16);
}

// ---------------- CSR build: rank + scan + place ----------------

__global__ void rank_count_kernel(const int* __restrict__ ei, int E,
                                  int* __restrict__ cursor, int* __restrict__ rank) {
    int e = blockIdx.x * blockDim.x + threadIdx.x;
    if (e < E) rank[e] = atomicAdd(&cursor[ei[E + e]], 1);
}

__global__ __launch_bounds__(1024) void scan_stage1(const int* __restrict__ deg, int N,
                                                    int* __restrict__ row_start,
                                                    int* __restrict__ partials) {
    __shared__ int wsum[16];
    int tid = threadIdx.x, lane = tid & 63, wid = tid >> 6;
    int i = blockIdx.x * 1024 + tid;
    int v = (i < N) ? deg[i] : 0;
    int x = v;
    #pragma unroll
    for (int off = 1; off < 64; off <<= 1) {
        int t = __shfl_up(x, off);
        if (lane >= off) x += t;
    }
    if (lane == 63) wsum[wid] = x;
    __syncthreads();
    if (tid == 0) {
        int acc = 0;
        #pragma unroll
        for (int w = 0; w < 16; ++w) { int t = wsum[w]; wsum[w] = acc; acc += t; }
        partials[blockIdx.x] = acc;
    }
    __syncthreads();
    if (i < N) row_start[i] = wsum[wid] + (x - v);
}

__global__ __launch_bounds__(1024) void scan_stage2(int* __restrict__ partials, int NB) {
    __shared__ int wsum[16];
    int tid = threadIdx.x, lane = tid & 63, wid = tid >> 6;
    int v = (tid < NB) ? partials[tid] : 0;
    int x = v;
    #pragma unroll
    for (int off = 1; off < 64; off <<= 1) {
        int t = __shfl_up(x, off);
        if (lane >= off) x += t;
    }
    if (lane == 63) wsum[wid] = x;
    __syncthreads();
    if (tid == 0) {
        int acc = 0;
        #pragma unroll
        for (int w = 0; w < 16; ++w) { int t = wsum[w]; wsum[w] = acc; acc += t; }
        partials[NB] = acc;
    }
    __syncthreads();
    if (tid < NB) partials[tid] = wsum[wid] + (x - v);
}

__global__ __launch_bounds__(1024) void scan_stage3(int* __restrict__ row_start,
                                                    const int* __restrict__ partials,
                                                    int N, int NB) {
    int i = blockIdx.x * 1024 + threadIdx.x;
    if (i < N) row_start[i] += partials[blockIdx.x];
    if (i == 0) row_start[N] = partials[NB];
}

__global__ void place_kernel(const int* __restrict__ ei, int E,
                             const int* __restrict__ row_start,
                             const int* __restrict__ rank, int* __restrict__ col) {
    int e = blockIdx.x * blockDim.x + threadIdx.x;
    if (e < E) {
        int d = ei[E + e];
        __builtin_nontemporal_store(ei[e], &col[row_start[d] + rank[e]]);
    }
}

// ---------------- conversions ----------------

__global__ void to_bf16_kernel(const float* __restrict__ in, u32* __restrict__ out, int n8) {
    int i = blockIdx.x * 256 + threadIdx.x;
    if (i >= n8) return;
    const float4* p = (const float4*)in + (size_t)i * 2;
    float4 a = p[0], b = p[1];
    uint4 o;
    o.x = pack_bf(a.x, a.y);
    o.y = pack_bf(a.z, a.w);
    o.z = pack_bf(b.x, b.y);
    o.w = pack_bf(b.z, b.w);
    ((uint4*)out)[i] = o;
}

// all 3 layers in one launch: Wcat_l[j][k] = (k<128 ? Wl[j][k] : Wr[j][k-128])
__global__ void build_wcat_all(const float* __restrict__ Wl0, const float* __restrict__ Wr0,
                               const float* __restrict__ Wl1, const float* __restrict__ Wr1,
                               const float* __restrict__ Wl2, const float* __restrict__ Wr2,
                               u16* __restrict__ Wcat) {
    int idx = blockIdx.x * 256 + threadIdx.x;   // 3*32768 total
    int l = idx >> 15;
    int r = idx & 32767;
    int j = r >> 8, k = r & 255;
    const float* Wl = (l == 0) ? Wl0 : (l == 1) ? Wl1 : Wl2;
    const float* Wr = (l == 0) ? Wr0 : (l == 1) ? Wr1 : Wr2;
    float v = (k < 128) ? Wl[j * 128 + k] : Wr[j * 128 + (k - 128)];
    Wcat[idx] = f2bf(v);
}

// ---------------- mean aggregation (bf16 in, bf16 out) ----------------
// one wave per node; lane handles 2 channels; batch ladder 16/8/4/2/1 so a
// deg~16 row completes in ~1-2 dependent memory rounds (MLP-maximizing).

template <int B>
static __device__ __forceinline__ void gather_batch(const u32* __restrict__ h32,
                                                    const int* __restrict__ col,
                                                    int p, int lane,
                                                    float& ax, float& ay) {
    int c[B];
    #pragma unroll
    for (int q = 0; q < B; ++q) c[q] = col[p + q];
    u32 u[B];
    #pragma unroll
    for (int q = 0; q < B; ++q) u[q] = h32[(size_t)c[q] * 64 + lane];
    #pragma unroll
    for (int q = 0; q < B; ++q) { ax += bf_lo(u[q]); ay += bf_hi(u[q]); }
}

__global__ __launch_bounds__(256) void agg_bf16(const u32* __restrict__ h32,   // [N][64]
                                                const int* __restrict__ row_start,
                                                const int* __restrict__ col,
                                                u32* __restrict__ agg32, int N) {
    int node = blockIdx.x * 4 + (threadIdx.x >> 6);
    node = __builtin_amdgcn_readfirstlane(node);
    if (node >= N) return;
    int lane = threadIdx.x & 63;
    int s0 = row_start[node], s1 = row_start[node + 1];
    float ax = 0.f, ay = 0.f;
    int p = s0;
    while (p + 16 <= s1) { gather_batch<16>(h32, col, p, lane, ax, ay); p += 16; }
    if (p + 8 <= s1)     { gather_batch<8>(h32, col, p, lane, ax, ay);  p += 8; }
    if (p + 4 <= s1)     { gather_batch<4>(h32, col, p, lane, ax, ay);  p += 4; }
    if (p + 2 <= s1)     { gather_batch<2>(h32, col, p, lane, ax, ay);  p += 2; }
    if (p < s1)          { gather_batch<1>(h32, col, p, lane, ax, ay); }
    float inv = 1.0f / fmaxf((float)(s1 - s0), 1.0f);
    agg32[(size_t)node * 64 + lane] = pack_bf(ax * inv, ay * inv);
}

// ---------------- fused dual GEMM via MFMA ----------------
// out[n,j] = [relu]( sum_k A[n,k]*Wcat[j,k] + bias[j] ),  A = [agg | h], K=256
// block: 256 thr = 4 waves; tile 64 rows x 128 cols; wave w: cols [w*32, w*32+32)

template <bool RELU, bool OUT_F32>
__global__ __launch_bounds__(256) void gemm_mfma(const u16* __restrict__ aggb,  // [N][128]
                                                 const u16* __restrict__ hb,    // [N][128]
                                                 const u16* __restrict__ Wcat,  // [128][256]
                                                 const float* __restrict__ bias,
                                                 u16* __restrict__ out_bf,
                                                 float* __restrict__ out_f32, int N) {
    __shared__ u16 s_a[64 * 256];   // 32 KB, XOR-swizzled rows
    int tid = threadIdx.x;
    int base = blockIdx.x * 64;
    int nrows = N - base; if (nrows > 64) nrows = 64;

    #pragma unroll
    for (int i = 0; i < 8; ++i) {
        int c = tid + i * 256;
        int row = c >> 5;
        int c16 = c & 31;
        int kbyte = (c16 * 16) ^ ((row & 7) << 4);
        uint4 v = make_uint4(0u, 0u, 0u, 0u);
        if (row < nrows) {
            const u16* src = (c16 < 16) ? (aggb + (size_t)(base + row) * 128 + c16 * 8)
                                        : (hb + (size_t)(base + row) * 128 + (c16 - 16) * 8);
            v = *(const uint4*)src;
        }
        *(uint4*)((char*)s_a + row * 512 + kbyte) = v;
    }
    __syncthreads();

    int lane = tid & 63;
    int wid = tid >> 6;
    int colbase = wid * 32;
    int jb = lane & 15;
    int kq = (lane >> 4) * 8;

    bf16x8 bfr[8][2];
    #pragma unroll
    for (int ks = 0; ks < 8; ++ks)
        #pragma unroll
        for (int n = 0; n < 2; ++n) {
            int j = colbase + n * 16 + jb;
            bfr[ks][n] = *(const bf16x8*)(Wcat + (size_t)j * 256 + ks * 32 + kq);
        }

    f32x4 acc[4][2];
    #pragma unroll
    for (int m = 0; m < 4; ++m)
        #pragma unroll
        for (int n = 0; n < 2; ++n)
            acc[m][n] = (f32x4){0.f, 0.f, 0.f, 0.f};

    #pragma unroll
    for (int ks = 0; ks < 8; ++ks) {
        bf16x8 afr[4];
        #pragma unroll
        for (int m = 0; m < 4; ++m) {
            int row = m * 16 + jb;
            int kbyte = (ks * 64 + kq * 2) ^ ((row & 7) << 4);
            afr[m] = *(const bf16x8*)((const char*)s_a + row * 512 + kbyte);
        }
        #pragma unroll
        for (int m = 0; m < 4; ++m)
            #pragma unroll
            for (int n = 0; n < 2; ++n)
                acc[m][n] = __builtin_amdgcn_mfma_f32_16x16x32_bf16(afr[m], bfr[ks][n],
                                                                    acc[m][n], 0, 0, 0);
    }

    float bv[2];
    #pragma unroll
    for (int n = 0; n < 2; ++n) bv[n] = bias[colbase + n * 16 + jb];

    #pragma unroll
    for (int m = 0; m < 4; ++m)
        #pragma unroll
        for (int n = 0; n < 2; ++n) {
            int colj = colbase + n * 16 + jb;
            #pragma unroll
            for (int r = 0; r < 4; ++r) {
                int row = m * 16 + (lane >> 4) * 4 + r;
                if (row < nrows) {
                    float v = acc[m][n][r] + bv[n];
                    if (RELU) v = fmaxf(v, 0.f);
                    size_t o = (size_t)(base + row) * 128 + colj;
                    if (OUT_F32) out_f32[o] = v;
                    else out_bf[o] = f2bf(v);
                }
            }
        }
}

// ---------------- launch ----------------

extern "C" void kernel_launch(void* const* d_in, const int* in_sizes, int n_in,
                              void* d_out, int out_size, void* d_ws, size_t ws_size,
                              hipStream_t stream) {
    const float* x   = (const float*)d_in[0];
    const int*   ei  = (const int*)d_in[1];
    const float* Wl0 = (const float*)d_in[2];
    const float* bl0 = (const float*)d_in[3];
    const float* Wr0 = (const float*)d_in[4];
    const float* Wl1 = (const float*)d_in[5];
    const float* bl1 = (const float*)d_in[6];
    const float* Wr1 = (const float*)d_in[7];
    const float* Wl2 = (const float*)d_in[8];
    const float* bl2 = (const float*)d_in[9];
    const float* Wr2 = (const float*)d_in[10];

    const int N = in_sizes[0] / D;
    const int E = in_sizes[1] / 2;
    const int NB = (N + 1023) / 1024;

    char* ws = (char*)d_ws;
    size_t off = 0;
    auto alloc = [&](size_t bytes) {
        void* p = ws + off;
        off = (off + bytes + 255) & ~(size_t)255;
        return p;
    };
    u16* xb        = (u16*)alloc((size_t)N * D * 2);   // layer-0 input; reused as h2b
    u16* h1b       = (u16*)alloc((size_t)N * D * 2);
    u16* aggb      = (u16*)alloc((size_t)N * D * 2);
    u16* Wcat      = (u16*)alloc(3 * (size_t)D * 256 * 2);
    int* cursor    = (int*)alloc((size_t)N * 4);       // becomes deg
    int* row_start = (int*)alloc((size_t)(N + 1) * 4);
    int* partials  = (int*)alloc((size_t)(NB + 1) * 4);
    int* rank      = (int*)alloc((size_t)E * 4);
    int* colv      = (int*)alloc((size_t)E * 4);
    (void)ws_size; (void)n_in; (void)out_size;
    u16* h2b = xb;   // alias: xb dead after layer-1 GEMM

    hipMemsetAsync(cursor, 0, (size_t)N * 4, stream);

    build_wcat_all<<<384, 256, 0, stream>>>(Wl0, Wr0, Wl1, Wr1, Wl2, Wr2, Wcat);

    int n8 = N * D / 8;
    to_bf16_kernel<<<(n8 + 255) / 256, 256, 0, stream>>>(x, (u32*)xb, n8);

    // CSR
    int eb = (E + 255) / 256;
    rank_count_kernel<<<eb, 256, 0, stream>>>(ei, E, cursor, rank);
    scan_stage1<<<NB, 1024, 0, stream>>>(cursor, N, row_start, partials);
    scan_stage2<<<1, 1024, 0, stream>>>(partials, NB);
    scan_stage3<<<NB, 1024, 0, stream>>>(row_start, partials, N, NB);
    place_kernel<<<eb, 256, 0, stream>>>(ei, E, row_start, rank, colv);

    float* out = (float*)d_out;
    int agrid = (N + 3) / 4;
    int ggrid = (N + 63) / 64;

    // layer 0: xb -> h1b (relu)
    agg_bf16<<<agrid, 256, 0, stream>>>((const u32*)xb, row_start, colv, (u32*)aggb, N);
    gemm_mfma<true, false><<<ggrid, 256, 0, stream>>>(aggb, xb, Wcat + 0 * D * 256, bl0,
                                                      h1b, nullptr, N);
    // layer 1: h1b -> h2b (relu)
    agg_bf16<<<agrid, 256, 0, stream>>>((const u32*)h1b, row_start, colv, (u32*)aggb, N);
    gemm_mfma<true, false><<<ggrid, 256, 0, stream>>>(aggb, h1b, Wcat + 1 * D * 256, bl1,
                                                      h2b, nullptr, N);
    // layer 2: h2b -> d_out (f32, no relu)
    agg_bf16<<<agrid, 256, 0, stream>>>((const u32*)h2b, row_start, colv, (u32*)aggb, N);
    gemm_mfma<false, true><<<ggrid, 256, 0, stream>>>(aggb, h2b, Wcat + 2 * D * 256, bl2,
                                                      nullptr, out, N);
}